// Round 1
// baseline (356.126 us; speedup 1.0000x reference)
//
#include <hip/hip_runtime.h>

// EPN layer: B=8, N=256, DH=32, DX=3, DQ=1, DE=8, H1=H2=32, DIN=80.
// Factorization: layer1 = relu(Pa[i] + Pb[j] + e_ij@W1e + b1)
//   Pa[n] = atom_n @ W1[0:36],  Pb[n] = atom_n @ W1[36:72]  (per-atom, cheap)
//   e_ij@W1e shared between the (i,j) and (j,i)-swapped MLP evals.
// b3 cancels in 0.5*(elec_ij - elec_ji) and is dropped.

#define NATOM 256
#define TOT_ATOMS 2048   // B*N

// ---- Kernel A: per-atom projections, transposed layout P[c][atom], c = which*32+u
__global__ __launch_bounds__(256) void atom_proj_kernel(
    const float* __restrict__ x, const float* __restrict__ h,
    const float* __restrict__ q, const float* __restrict__ W1,
    float* __restrict__ P)
{
    // 512 blocks x 256 threads. c uniform per block (scalar weight loads).
    const int bid   = blockIdx.x;
    const int c     = bid >> 3;                      // 0..63, block-uniform
    const int n     = ((bid & 7) << 8) + threadIdx.x; // atom 0..2047
    const int which = c >> 5;                        // 0 -> rows 0..35, 1 -> rows 36..71
    const int u     = c & 31;
    const float* Wcol = W1 + which * 36 * 32 + u;    // column u, stride 32

    float acc = 0.f;
    acc += x[n * 3 + 0] * Wcol[0 * 32];
    acc += x[n * 3 + 1] * Wcol[1 * 32];
    acc += x[n * 3 + 2] * Wcol[2 * 32];
#pragma unroll
    for (int k = 0; k < 32; ++k)
        acc += h[n * 32 + k] * Wcol[(3 + k) * 32];
    acc += q[n] * Wcol[35 * 32];

    P[c * TOT_ATOMS + n] = acc;
}

// ---- Kernel B: one block per (b,i) row, thread j per ordered pair
__global__ __launch_bounds__(256) void pair_kernel(
    const float* __restrict__ e, const float* __restrict__ mask,
    const float* __restrict__ q, const float* __restrict__ P,
    const float* __restrict__ W1, const float* __restrict__ b1,
    const float* __restrict__ W2, const float* __restrict__ b2,
    const float* __restrict__ W3, float* __restrict__ out)
{
    const int row = blockIdx.x;          // b*256 + i  (also atom index of i)
    const int b   = row >> 8;
    const int j   = threadIdx.x;
    const int col = (b << 8) + j;        // atom index of j
    const float* Pa = P;                 // [32][2048]
    const float* Pb = P + 32 * TOT_ATOMS;

    // per-thread pair data
    const float* ep = e + (size_t)(row * NATOM + j) * 8;
    const float4 ev0 = *(const float4*)(ep);
    const float4 ev1 = *(const float4*)(ep + 4);
    float e8[8] = {ev0.x, ev0.y, ev0.z, ev0.w, ev1.x, ev1.y, ev1.z, ev1.w};

    const float m = mask[row * NATOM + j];
    float mx = e8[0];
#pragma unroll
    for (int k = 1; k < 8; ++k) mx = fmaxf(mx, e8[k]);
    const float near = (mx > 1e-5f) ? 1.0f : 0.0f;
    const float g = 0.5f * m * near;

    // layer 1 (both orientations share the e-projection)
    float zij[32], zji[32];
#pragma unroll
    for (int u = 0; u < 32; ++u) {
        float ez = b1[u];
#pragma unroll
        for (int de = 0; de < 8; ++de)
            ez += e8[de] * W1[(72 + de) * 32 + u];     // uniform addr -> s_load
        const float pai = Pa[u * TOT_ATOMS + row];     // block-uniform
        const float pbi = Pb[u * TOT_ATOMS + row];     // block-uniform
        const float paj = Pa[u * TOT_ATOMS + col];     // coalesced per-thread
        const float pbj = Pb[u * TOT_ATOMS + col];     // coalesced per-thread
        zij[u] = fmaxf(pai + pbj + ez, 0.f);
        zji[u] = fmaxf(paj + pbi + ez, 0.f);
    }

    // layers 2+3 fused; weight loads shared between both evals
    float oij = 0.f, oji = 0.f;
#pragma unroll
    for (int u = 0; u < 32; ++u) {
        float aij = b2[u], aji = aij;
#pragma unroll
        for (int k = 0; k < 32; ++k) {
            const float w = W2[k * 32 + u];            // uniform addr -> s_load
            aij += zij[k] * w;
            aji += zji[k] * w;
        }
        const float w3 = W3[u];
        oij += fmaxf(aij, 0.f) * w3;
        oji += fmaxf(aji, 0.f) * w3;
    }

    float v = (oij - oji) * g;

    // block reduction over j (4 waves of 64)
#pragma unroll
    for (int off = 32; off > 0; off >>= 1)
        v += __shfl_down(v, off, 64);
    __shared__ float red[4];
    if ((threadIdx.x & 63) == 0) red[threadIdx.x >> 6] = v;
    __syncthreads();
    if (threadIdx.x == 0)
        out[row] = q[row] + (red[0] + red[1] + red[2] + red[3]);
}

extern "C" void kernel_launch(void* const* d_in, const int* in_sizes, int n_in,
                              void* d_out, int out_size, void* d_ws, size_t ws_size,
                              hipStream_t stream)
{
    const float* h    = (const float*)d_in[0];
    const float* e    = (const float*)d_in[1];
    const float* x    = (const float*)d_in[2];
    const float* q    = (const float*)d_in[3];
    const float* mask = (const float*)d_in[4];
    const float* W1   = (const float*)d_in[5];
    const float* b1   = (const float*)d_in[6];
    const float* W2   = (const float*)d_in[7];
    const float* b2   = (const float*)d_in[8];
    const float* W3   = (const float*)d_in[9];
    // b3 cancels in the antisymmetric difference.

    float* P = (float*)d_ws;  // 2 * 32 * 2048 floats = 512 KB

    atom_proj_kernel<<<512, 256, 0, stream>>>(x, h, q, W1, P);
    pair_kernel<<<TOT_ATOMS, 256, 0, stream>>>(e, mask, q, P, W1, b1, W2, b2, W3,
                                               (float*)d_out);
}

// Round 3
// 161.003 us; speedup vs baseline: 2.2119x; 2.2119x over previous
//
#include <hip/hip_runtime.h>

// EPN layer: B=8, N=256, DH=32, DX=3, DQ=1, DE=8, H1=H2=32, DIN=80.
// Factorization: layer1 = relu(Pa[i] + Pb[j] + e_ij@W1e + b1)
//   Pa[n] = atom_n @ W1[0:36],  Pb[n] = atom_n @ W1[36:72]  (per-atom, cheap)
//   e_ij@W1e shared between the (i,j) and (j,i)-swapped MLP evals.
// b3 cancels in 0.5*(elec_ij - elec_ji) and is dropped.
//
// R1 lesson: with z[64] held as loads-derived temps, the compiler picked a
// 44-VGPR allocation and REMATERIALIZED layer-1 inside the unrolled layer-2
// loop (~32x redundant VALU work -> 90% VALUBusy at 6% of FLOP peak).
// Fix: loop interchange so the live state is accumulators aij/aji[32].
// R2 lesson: LDS staging guard `t < 288` with 256 threads left atom 7's
// features unwritten -> absmax 1.5e4. Use a strided staging loop.

#define NATOM 256
#define TOT_ATOMS 2048   // B*N

// ---- Kernel A: per-atom projections, transposed layout P[c][atom], c = which*32+u
// 256 blocks x 256 threads; block handles 8 atoms; thread = (atom_local, u).
__global__ __launch_bounds__(256) void atom_proj_kernel(
    const float* __restrict__ x, const float* __restrict__ h,
    const float* __restrict__ q, const float* __restrict__ W1,
    float* __restrict__ P)
{
    const int a  = threadIdx.x >> 5;   // 0..7
    const int u  = threadIdx.x & 31;   // 0..31
    const int n0 = blockIdx.x * 8;

    __shared__ float sd[8][36];        // atom features in W1-row order: x(3),h(32),q(1)
    for (int idx = threadIdx.x; idx < 8 * 36; idx += 256) {
        const int aa = idx / 36, r = idx % 36;
        const int n = n0 + aa;
        float v;
        if (r < 3)       v = x[n * 3 + r];
        else if (r < 35) v = h[n * 32 + (r - 3)];
        else             v = q[n];
        sd[aa][r] = v;
    }
    __syncthreads();

    float pa = 0.f, pb = 0.f;
#pragma unroll
    for (int r = 0; r < 36; ++r) {
        const float d = sd[a][r];
        pa += d * W1[r * 32 + u];          // coalesced across u
        pb += d * W1[(36 + r) * 32 + u];
    }
    const int n = n0 + a;
    P[u * TOT_ATOMS + n] = pa;
    P[(32 + u) * TOT_ATOMS + n] = pb;
}

// ---- Kernel B: one block per (b,i) row, thread j per ordered pair
__global__ __launch_bounds__(256) void pair_kernel(
    const float* __restrict__ e, const float* __restrict__ mask,
    const float* __restrict__ q, const float* __restrict__ P,
    const float* __restrict__ W1, const float* __restrict__ b1,
    const float* __restrict__ W2, const float* __restrict__ b2,
    const float* __restrict__ W3, float* __restrict__ out)
{
    const int row = blockIdx.x;          // b*256 + i  (also atom index of i)
    const int b   = row >> 8;
    const int j   = threadIdx.x;
    const int col = (b << 8) + j;        // atom index of j
    const float* Pa = P;                 // [32][2048]
    const float* Pb = P + 32 * TOT_ATOMS;

    // per-thread pair data
    const float* ep = e + (size_t)(row * NATOM + j) * 8;
    const float4 ev0 = *(const float4*)(ep);
    const float4 ev1 = *(const float4*)(ep + 4);
    float e8[8] = {ev0.x, ev0.y, ev0.z, ev0.w, ev1.x, ev1.y, ev1.z, ev1.w};

    const float m = mask[row * NATOM + j];
    float mx = e8[0];
#pragma unroll
    for (int k = 1; k < 8; ++k) mx = fmaxf(mx, e8[k]);
    const float near = (mx > 1e-5f) ? 1.0f : 0.0f;
    const float g = 0.5f * m * near;

    // layer-2 accumulators (long-lived; forces register allocation)
    float aij[32], aji[32];
#pragma unroll
    for (int u = 0; u < 32; ++u) { const float bb = b2[u]; aij[u] = bb; aji[u] = bb; }

    // stream layer-1 one k at a time, immediately consumed by layer 2
#pragma unroll
    for (int k = 0; k < 32; ++k) {
        float ez = b1[k];
#pragma unroll
        for (int de = 0; de < 8; ++de)
            ez += e8[de] * W1[(72 + de) * 32 + k];     // uniform addr
        const float pai = Pa[k * TOT_ATOMS + row];     // block-uniform
        const float pbi = Pb[k * TOT_ATOMS + row];     // block-uniform
        const float paj = Pa[k * TOT_ATOMS + col];     // coalesced per-thread
        const float pbj = Pb[k * TOT_ATOMS + col];     // coalesced per-thread
        const float zij = fmaxf(pai + pbj + ez, 0.f);
        const float zji = fmaxf(paj + pbi + ez, 0.f);
#pragma unroll
        for (int u = 0; u < 32; ++u) {
            const float w = W2[k * 32 + u];            // uniform addr
            aij[u] += zij * w;
            aji[u] += zji * w;
        }
    }

    // layer 3
    float oij = 0.f, oji = 0.f;
#pragma unroll
    for (int u = 0; u < 32; ++u) {
        const float w3 = W3[u];
        oij += fmaxf(aij[u], 0.f) * w3;
        oji += fmaxf(aji[u], 0.f) * w3;
    }

    float v = (oij - oji) * g;

    // block reduction over j (4 waves of 64)
#pragma unroll
    for (int off = 32; off > 0; off >>= 1)
        v += __shfl_down(v, off, 64);
    __shared__ float red[4];
    if ((threadIdx.x & 63) == 0) red[threadIdx.x >> 6] = v;
    __syncthreads();
    if (threadIdx.x == 0)
        out[row] = q[row] + (red[0] + red[1] + red[2] + red[3]);
}

extern "C" void kernel_launch(void* const* d_in, const int* in_sizes, int n_in,
                              void* d_out, int out_size, void* d_ws, size_t ws_size,
                              hipStream_t stream)
{
    const float* h    = (const float*)d_in[0];
    const float* e    = (const float*)d_in[1];
    const float* x    = (const float*)d_in[2];
    const float* q    = (const float*)d_in[3];
    const float* mask = (const float*)d_in[4];
    const float* W1   = (const float*)d_in[5];
    const float* b1   = (const float*)d_in[6];
    const float* W2   = (const float*)d_in[7];
    const float* b2   = (const float*)d_in[8];
    const float* W3   = (const float*)d_in[9];
    // b3 cancels in the antisymmetric difference.

    float* P = (float*)d_ws;  // 2 * 32 * 2048 floats = 512 KB

    atom_proj_kernel<<<256, 256, 0, stream>>>(x, h, q, W1, P);
    pair_kernel<<<TOT_ATOMS, 256, 0, stream>>>(e, mask, q, P, W1, b1, W2, b2, W3,
                                               (float*)d_out);
}

// Round 5
// 157.757 us; speedup vs baseline: 2.2574x; 1.0206x over previous
//
#include <hip/hip_runtime.h>

// EPN layer: B=8, N=256, DH=32, DX=3, DQ=1, DE=8, H1=H2=32, DIN=80.
// Factorization: layer1 = relu(Pa[i] + Pb[j] + e_ij@W1e + b1)
//   Pa[n] = atom_n @ W1[0:36],  Pb[n] = atom_n @ W1[36:72]  (per-atom, cheap)
//   e_ij@W1e shared between the (i,j) and (j,i)-swapped MLP evals.
// b3 cancels in 0.5*(elec_ij - elec_ji) and is dropped.
//
// R1: compiler rematerialized layer-1 inside layer-2 (44 VGPR, 90% busy, 6% useful).
// R3: compiler FISSIONED the u-loop (VGPR=52 -> accs not all live; 2x layer-1 work).
//     Fix: __launch_bounds__(256,4) (VGPR budget 128) + asm volatile pin on z
//     (exactly-once evaluation -> fission/remat illegal).
// R4: atom_proj stored q at row offset 36 (pad) instead of 35 -> sd[..+35]
//     read uninitialized. Layout is x:0-2, h:3-34, q:35, pad:36.

#define NATOM 256
#define TOT_ATOMS 2048   // B*N

// ---- Kernel A: per-atom projections, transposed layout P[c][atom].
// 8 blocks x 256 threads; one thread per atom; coalesced P writes.
__global__ __launch_bounds__(256) void atom_proj_kernel(
    const float* __restrict__ x, const float* __restrict__ h,
    const float* __restrict__ q, const float* __restrict__ W1,
    float* __restrict__ P)
{
    const int t  = threadIdx.x;
    const int n0 = blockIdx.x * 256;

    __shared__ float sd[256 * 37];   // [atom][37]: x(3), h(32), q(1), pad(1)
    // x: 768 floats, coalesced
    for (int i = t; i < 768; i += 256) {
        const int n = i / 3, r = i - n * 3;
        sd[n * 37 + r] = x[n0 * 3 + i];
    }
    // h: 2048 float4s, coalesced; (i&7)*4 keeps the 4 lanes inside one row
    {
        const float4* h4 = (const float4*)(h + (size_t)n0 * 32);
        for (int i = t; i < 2048; i += 256) {
            const float4 v = h4[i];
            const int n = i >> 3, k = (i & 7) * 4;
            float* p = &sd[n * 37 + 3 + k];
            p[0] = v.x; p[1] = v.y; p[2] = v.z; p[3] = v.w;
        }
    }
    sd[t * 37 + 35] = q[n0 + t];     // q at offset 35 (36 is pad)
    __syncthreads();

    float acc[64];
#pragma unroll
    for (int c = 0; c < 64; ++c) acc[c] = 0.f;
#pragma unroll
    for (int r = 0; r < 36; ++r) {
        const float f = sd[t * 37 + r];   // bank = (t*5+r)%32 -> 2-way max (free)
#pragma unroll
        for (int c = 0; c < 64; ++c) {
            // c<32: W1 rows [0,36); c>=32: rows [36,72). Uniform addrs -> s_load.
            const int rr = (c < 32) ? r : (36 + r);
            acc[c] += f * W1[rr * 32 + (c & 31)];
        }
    }
#pragma unroll
    for (int c = 0; c < 64; ++c)
        P[c * TOT_ATOMS + n0 + t] = acc[c];   // coalesced across t
}

// ---- Kernel B: one block per (b,i) row, thread j per ordered pair
__global__ __launch_bounds__(256, 4) void pair_kernel(
    const float* __restrict__ e, const float* __restrict__ mask,
    const float* __restrict__ q, const float* __restrict__ P,
    const float* __restrict__ W1, const float* __restrict__ b1,
    const float* __restrict__ W2, const float* __restrict__ b2,
    const float* __restrict__ W3, float* __restrict__ out)
{
    const int row = blockIdx.x;          // b*256 + i  (also atom index of i)
    const int b   = row >> 8;
    const int j   = threadIdx.x;
    const int col = (b << 8) + j;        // atom index of j
    const float* Pa = P;                 // [32][2048]
    const float* Pb = P + 32 * TOT_ATOMS;

    // per-thread pair data
    const float* ep = e + (size_t)(row * NATOM + j) * 8;
    const float4 ev0 = *(const float4*)(ep);
    const float4 ev1 = *(const float4*)(ep + 4);
    float e8[8] = {ev0.x, ev0.y, ev0.z, ev0.w, ev1.x, ev1.y, ev1.z, ev1.w};

    const float m = mask[row * NATOM + j];
    float mx = e8[0];
#pragma unroll
    for (int k = 1; k < 8; ++k) mx = fmaxf(mx, e8[k]);
    const float near = (mx > 1e-5f) ? 1.0f : 0.0f;
    const float g = 0.5f * m * near;

    // layer-2 accumulators (must stay live: 64 VGPRs)
    float aij[32], aji[32];
#pragma unroll
    for (int u = 0; u < 32; ++u) { const float bb = b2[u]; aij[u] = bb; aji[u] = bb; }

    // stream layer-1 one k at a time, immediately consumed by layer 2
#pragma unroll
    for (int k = 0; k < 32; ++k) {
        float ez = b1[k];
#pragma unroll
        for (int de = 0; de < 8; ++de)
            ez += e8[de] * W1[(72 + de) * 32 + k];     // uniform addr -> s_load
        const float pai = Pa[k * TOT_ATOMS + row];     // block-uniform -> s_load
        const float pbi = Pb[k * TOT_ATOMS + row];
        const float paj = Pa[k * TOT_ATOMS + col];     // coalesced per-thread
        const float pbj = Pb[k * TOT_ATOMS + col];
        float zij = fmaxf(pai + pbj + ez, 0.f);
        float zji = fmaxf(paj + pbi + ez, 0.f);
        // volatile asm: z must be computed exactly once -> no fission/remat
        asm volatile("" : "+v"(zij), "+v"(zji));
#pragma unroll
        for (int u = 0; u < 32; ++u) {
            const float w = W2[k * 32 + u];            // uniform addr -> s_load
            aij[u] += zij * w;
            aji[u] += zji * w;
        }
    }

    // layer 3
    float oij = 0.f, oji = 0.f;
#pragma unroll
    for (int u = 0; u < 32; ++u) {
        const float w3 = W3[u];
        oij += fmaxf(aij[u], 0.f) * w3;
        oji += fmaxf(aji[u], 0.f) * w3;
    }

    float v = (oij - oji) * g;

    // block reduction over j (4 waves of 64)
#pragma unroll
    for (int off = 32; off > 0; off >>= 1)
        v += __shfl_down(v, off, 64);
    __shared__ float red[4];
    if ((threadIdx.x & 63) == 0) red[threadIdx.x >> 6] = v;
    __syncthreads();
    if (threadIdx.x == 0)
        out[row] = q[row] + (red[0] + red[1] + red[2] + red[3]);
}

extern "C" void kernel_launch(void* const* d_in, const int* in_sizes, int n_in,
                              void* d_out, int out_size, void* d_ws, size_t ws_size,
                              hipStream_t stream)
{
    const float* h    = (const float*)d_in[0];
    const float* e    = (const float*)d_in[1];
    const float* x    = (const float*)d_in[2];
    const float* q    = (const float*)d_in[3];
    const float* mask = (const float*)d_in[4];
    const float* W1   = (const float*)d_in[5];
    const float* b1   = (const float*)d_in[6];
    const float* W2   = (const float*)d_in[7];
    const float* b2   = (const float*)d_in[8];
    const float* W3   = (const float*)d_in[9];
    // b3 cancels in the antisymmetric difference.

    float* P = (float*)d_ws;  // 2 * 32 * 2048 floats = 512 KB

    atom_proj_kernel<<<8, 256, 0, stream>>>(x, h, q, W1, P);
    pair_kernel<<<TOT_ATOMS, 256, 0, stream>>>(e, mask, q, P, W1, b1, W2, b2, W3,
                                               (float*)d_out);
}

// Round 6
// 107.206 us; speedup vs baseline: 3.3219x; 1.4715x over previous
//
#include <hip/hip_runtime.h>

// EPN layer: B=8, N=256, DH=32, DX=3, DQ=1, DE=8, H1=H2=32, DIN=80.
// layer1 = relu(Pa[i] + Pb'[j] + e_ij@W1e), Pb' has b1 folded in.
// b3 cancels in 0.5*(elec_ij - elec_ji).
//
// R1: remat (44 VGPR). R3: fission (52 VGPR). R5: accs forced to AGPRs
//   (VGPR stuck at 52, ~2x VALU bloat from acc moves); 8-block atom_proj
//   spilled acc[64] -> ~100us. This round: layer-2 via MFMA 32x32x16_bf16
//   computed TRANSPOSED (A=W2^T, B=Z^T) so C cols = j, epilogue per-lane;
//   layer-1 stays VALU -> bf16 Z in LDS; P relaid to [atom][64], b1 folded.

#define NATOM 256
#define TOT_ATOMS 2048
#define ZS 40   // ushort elems per Z row: 80 B = 16B-aligned, 20-bank stride

typedef __bf16 bf16x8 __attribute__((ext_vector_type(8)));
typedef float  f32x16 __attribute__((ext_vector_type(16)));

__device__ __forceinline__ unsigned int pk2(float a, float b) {
    unsigned short lo = __builtin_bit_cast(unsigned short, (__bf16)a);
    unsigned short hi = __builtin_bit_cast(unsigned short, (__bf16)b);
    return (unsigned int)lo | ((unsigned int)hi << 16);
}

// ---- Kernel A: per-atom projections, P[atom][64]: c<32 = Pa, c>=32 = Pb+b1.
// 256 blocks x 256 threads; thread = (atom_local 0..7, u 0..31); 2 accs.
__global__ __launch_bounds__(256) void atom_proj_kernel(
    const float* __restrict__ x, const float* __restrict__ h,
    const float* __restrict__ q, const float* __restrict__ W1,
    const float* __restrict__ b1, float* __restrict__ P)
{
    const int a  = threadIdx.x >> 5;   // 0..7
    const int u  = threadIdx.x & 31;   // 0..31
    const int n0 = blockIdx.x * 8;

    __shared__ float sd[8][37];        // x(3), h(32), q(1), pad
    for (int idx = threadIdx.x; idx < 8 * 36; idx += 256) {
        const int aa = idx / 36, r = idx - aa * 36;
        const int n = n0 + aa;
        float v;
        if (r < 3)       v = x[n * 3 + r];
        else if (r < 35) v = h[n * 32 + (r - 3)];
        else             v = q[n];
        sd[aa][r] = v;
    }
    __syncthreads();

    float pa = 0.f, pb = b1[u];        // fold b1 into the Pb side
#pragma unroll
    for (int r = 0; r < 36; ++r) {
        const float d = sd[a][r];      // broadcast across the 32 u-lanes
        pa += d * W1[r * 32 + u];
        pb += d * W1[(36 + r) * 32 + u];
    }
    const int n = n0 + a;
    P[(size_t)n * 64 + u]      = pa;
    P[(size_t)n * 64 + 32 + u] = pb;
}

// ---- Kernel B: one block per (b,i) row; VALU layer-1 -> bf16 Z in LDS ->
//      MFMA layer-2 (transposed) -> per-lane layer-3/antisym epilogue.
__global__ __launch_bounds__(256, 3) void pair_kernel(
    const float* __restrict__ e, const float* __restrict__ mask,
    const float* __restrict__ q, const float* __restrict__ P,
    const float* __restrict__ W1, const float* __restrict__ W2,
    const float* __restrict__ b2, const float* __restrict__ W3,
    float* __restrict__ out)
{
    const int row = blockIdx.x;          // b*256 + i == atom index of i
    const int b   = row >> 8;
    const int j   = threadIdx.x;
    const int col = (b << 8) + j;        // atom index of j

    __shared__ unsigned short Zij[256 * ZS];
    __shared__ unsigned short Zji[256 * ZS];
    __shared__ unsigned short W2t[32 * ZS];   // W2t[u][k] = W2[k][u], bf16
    __shared__ float g_lds[256];
    __shared__ float red[4];

    // ---- per-pair scalars
    const float* ep = e + (size_t)(row * NATOM + j) * 8;
    const float4 ev0 = ((const float4*)ep)[0];
    const float4 ev1 = ((const float4*)ep)[1];
    float e8[8] = {ev0.x, ev0.y, ev0.z, ev0.w, ev1.x, ev1.y, ev1.z, ev1.w};
    const float m = mask[row * NATOM + j];
    float mx = e8[0];
#pragma unroll
    for (int k = 1; k < 8; ++k) mx = fmaxf(mx, e8[k]);
    const float near = (mx > 1e-5f) ? 1.0f : 0.0f;
    g_lds[j] = 0.5f * m * near;

    // ---- stage W2^T in bf16 (thread -> 4 entries)
    {
        const int u  = threadIdx.x >> 3;        // 0..31
        const int k0 = (threadIdx.x & 7) * 4;   // 0,4,..,28
        const unsigned int p0 = pk2(W2[(k0 + 0) * 32 + u], W2[(k0 + 1) * 32 + u]);
        const unsigned int p1 = pk2(W2[(k0 + 2) * 32 + u], W2[(k0 + 3) * 32 + u]);
        *(unsigned int*)&W2t[u * ZS + k0]     = p0;
        *(unsigned int*)&W2t[u * ZS + k0 + 2] = p1;
    }

    // ---- layer 1: z_ij/z_ji per k, pack bf16 pairs into LDS
    const float* Pi = P + (size_t)row * 64;   // uniform -> s_load
    const float* Pj = P + (size_t)col * 64;   // per-thread vector loads
#pragma unroll
    for (int kq = 0; kq < 8; ++kq) {
        const float4 paj4 = ((const float4*)Pj)[kq];
        const float4 pbj4 = ((const float4*)Pj)[8 + kq];
        const float* paj = (const float*)&paj4;
        const float* pbj = (const float*)&pbj4;
        float zij[4], zji[4];
#pragma unroll
        for (int kk = 0; kk < 4; ++kk) {
            const int k = kq * 4 + kk;
            float ez = 0.f;
#pragma unroll
            for (int de = 0; de < 8; ++de)
                ez += e8[de] * W1[(72 + de) * 32 + k];   // uniform -> s_load
            const float pai = Pi[k];        // uniform
            const float pbi = Pi[32 + k];   // uniform (has b1)
            zij[kk] = fmaxf(pai + pbj[kk] + ez, 0.f);
            zji[kk] = fmaxf(paj[kk] + pbi + ez, 0.f);
        }
        const unsigned int i0 = pk2(zij[0], zij[1]), i1 = pk2(zij[2], zij[3]);
        const unsigned int j0 = pk2(zji[0], zji[1]), j1 = pk2(zji[2], zji[3]);
        *(uint2*)&Zij[j * ZS + kq * 4] = make_uint2(i0, i1);
        *(uint2*)&Zji[j * ZS + kq * 4] = make_uint2(j0, j1);
    }
    __syncthreads();

    // ---- layer 2 via MFMA: C[u][j] = sum_k W2t[u][k] * Z[j][k]
    const int wave = threadIdx.x >> 6;
    const int lane = threadIdx.x & 63;
    const int lo = lane & 31;     // = u for A, = j-col for B/C
    const int h  = lane >> 5;     // k-half selector / C row offset

    const bf16x8 a0 = *(const bf16x8*)&W2t[lo * ZS + h * 8];        // k 0..15
    const bf16x8 a1 = *(const bf16x8*)&W2t[lo * ZS + 16 + h * 8];   // k 16..31

    float vacc = 0.f;
#pragma unroll
    for (int nt = 0; nt < 2; ++nt) {
        const int jt = (wave + nt * 4) * 32;     // j-tile base
        const int zo = (jt + lo) * ZS + h * 8;
        f32x16 cij = {0.f}, cji = {0.f};
        {
            const bf16x8 bz0 = *(const bf16x8*)&Zij[zo];
            const bf16x8 bz1 = *(const bf16x8*)&Zij[zo + 16];
            cij = __builtin_amdgcn_mfma_f32_32x32x16_bf16(a0, bz0, cij, 0, 0, 0);
            cij = __builtin_amdgcn_mfma_f32_32x32x16_bf16(a1, bz1, cij, 0, 0, 0);
        }
        {
            const bf16x8 bz0 = *(const bf16x8*)&Zji[zo];
            const bf16x8 bz1 = *(const bf16x8*)&Zji[zo + 16];
            cji = __builtin_amdgcn_mfma_f32_32x32x16_bf16(a0, bz0, cji, 0, 0, 0);
            cji = __builtin_amdgcn_mfma_f32_32x32x16_bf16(a1, bz1, cji, 0, 0, 0);
        }
        // epilogue: per lane, 16 u-values (u = (reg&3)+8*(reg>>2)+4h) for col j=jt+lo
        float d = 0.f;
#pragma unroll
        for (int reg = 0; reg < 16; ++reg) {
            const int u0 = (reg & 3) + 8 * (reg >> 2);
            const float b2v = h ? b2[u0 + 4] : b2[u0];   // cndmask of s-operands
            const float w3v = h ? W3[u0 + 4] : W3[u0];
            const float rij = fmaxf(cij[reg] + b2v, 0.f);
            const float rji = fmaxf(cji[reg] + b2v, 0.f);
            d += (rij - rji) * w3v;
        }
        d += __shfl_xor(d, 32, 64);              // complete the 32-u sum
        vacc += d * g_lds[jt + lo];
    }

    // wave sum (each j counted in both halves -> x2), then block sum
#pragma unroll
    for (int off = 1; off < 64; off <<= 1)
        vacc += __shfl_xor(vacc, off, 64);
    if (lane == 0) red[wave] = vacc;
    __syncthreads();
    if (threadIdx.x == 0)
        out[row] = q[row] + 0.5f * (red[0] + red[1] + red[2] + red[3]);
}

extern "C" void kernel_launch(void* const* d_in, const int* in_sizes, int n_in,
                              void* d_out, int out_size, void* d_ws, size_t ws_size,
                              hipStream_t stream)
{
    const float* h    = (const float*)d_in[0];
    const float* e    = (const float*)d_in[1];
    const float* x    = (const float*)d_in[2];
    const float* q    = (const float*)d_in[3];
    const float* mask = (const float*)d_in[4];
    const float* W1   = (const float*)d_in[5];
    const float* b1   = (const float*)d_in[6];
    const float* W2   = (const float*)d_in[7];
    const float* b2   = (const float*)d_in[8];
    const float* W3   = (const float*)d_in[9];
    // b3 cancels in the antisymmetric difference.

    float* P = (float*)d_ws;  // [2048][64] floats = 512 KB

    atom_proj_kernel<<<256, 256, 0, stream>>>(x, h, q, W1, b1, P);
    pair_kernel<<<TOT_ATOMS, 256, 0, stream>>>(e, mask, q, P, W1, W2, b2, W3,
                                               (float*)d_out);
}